// Round 2
// baseline (270.853 us; speedup 1.0000x reference)
//
#include <hip/hip_runtime.h>
#include <stdint.h>

#define AS1 __attribute__((address_space(1)))
#define AS3 __attribute__((address_space(3)))

typedef float   f32x4  __attribute__((ext_vector_type(4)));
typedef __bf16  bf16x8 __attribute__((ext_vector_type(8)));
typedef uint32_t u32x4 __attribute__((ext_vector_type(4)));

// Round-half-up fp32->bf16 pair pack: low16 = lo, high16 = hi.
__device__ __forceinline__ uint32_t pack_rnd(float lo, float hi) {
    uint32_t a = __float_as_uint(hi) + 0x8000u;
    uint32_t b = __float_as_uint(lo) + 0x8000u;
    return __builtin_amdgcn_perm(a, b, 0x07060302u); // bytes: a3 a2 b3 b2
}

// ---------------- wt_prep: w [512 c][1024 n] f32 -> wt [1024 n][512 c] bf16 ----------------
// LDS-tiled transpose; output written as full 1 KB contiguous rows per wave-instruction.
__global__ __launch_bounds__(256) void wt_prep(const float* __restrict__ w,
                                               uint16_t* __restrict__ wt) {
    __shared__ uint16_t tile[32][520];   // [n_local][c]; row = 1040 B (16 B multiple)
    const int tid = threadIdx.x;
    const int n0  = blockIdx.x * 32;
    const int nq  = tid & 7;             // n-quad within tile
    const int cr  = tid >> 3;            // c-row (0..31) per pass
#pragma unroll
    for (int p = 0; p < 16; ++p) {
        int c = p * 32 + cr;
        f32x4 q = *(const f32x4*)(w + (size_t)c * 1024 + n0 + nq * 4); // 128 B runs / 8 lanes
#pragma unroll
        for (int i = 0; i < 4; ++i)
            tile[nq * 4 + i][c] = (uint16_t)((__float_as_uint(q[i]) + 0x8000u) >> 16);
    }
    __syncthreads();
    const int l  = tid & 63;
    const int wv = tid >> 6;
#pragma unroll
    for (int rr = 0; rr < 8; ++rr) {
        int nl = wv * 8 + rr;
        u32x4 d = *(const u32x4*)&tile[nl][l * 8];                  // 16 B aligned
        *(u32x4*)(wt + (size_t)(n0 + nl) * 512 + l * 8) = d;        // wave = 1 KB contiguous
    }
}

// ---------------- Main kernel: D[n][m] = Wt · X, fused bias + pixel-shuffle ----------------
// BM=128, BN=128, BK=64, 256 threads (4 waves). Manual-waitcnt software pipeline:
//   X prefetch distance 2 (regs), W gll distance 1 (LDS dbuf); no vmcnt(0) drains except kt=7.
__global__ __launch_bounds__(256, 3) void tconv_gemm(const float* __restrict__ x,
                                                     const uint16_t* __restrict__ wt,
                                                     const float* __restrict__ bias,
                                                     float* __restrict__ out) {
    __shared__ uint16_t Ws[2][8192];   // [buf][128 n][64 k]
    __shared__ uint16_t Xs[8192];      // [128 m][64 k]

    const int tid  = threadIdx.x;
    const int l    = tid & 63;
    const int wv   = tid >> 6;
    const int l15  = l & 15;
    const int quad = l >> 4;

    // XCD-aware decode: the 8 nblk-variants of one mblk land on the same XCD, 8 bids apart.
    const int bid  = blockIdx.x;
    const int xcd  = bid & 7;
    const int jj   = bid >> 3;
    const int nblk = jj & 7;
    const int mblk = xcd * 32 + (jj >> 3);

    const int b  = mblk >> 5;
    const int p0 = (mblk & 31) * 128;
    const int n0 = nblk * 128;

    const float* xblk = x + ((size_t)b * 512) * 4096 + p0;

    // X staging: thread covers 8 k-rows x 4 m
    const int mq4 = (tid & 31) * 4;
    const int ko  = tid >> 5;
    const float* xsrc = xblk + (size_t)ko * 8 * 4096 + mq4;
    int xw_off[4];
#pragma unroll
    for (int mm = 0; mm < 4; ++mm) {
        int m = mq4 + mm;
        xw_off[mm] = m * 64 + ((ko ^ ((m >> 1) & 7)) << 3);
    }

    // W gll: lane (rr,cc); XOR swizzle applied to GLOBAL chunk; LDS base wave-uniform.
    const int rr = l >> 3, cc = l & 7;
    int wg_off[4], wl_off[4];
#pragma unroll
    for (int i = 0; i < 4; ++i) {
        int n_r  = wv * 32 + i * 8 + rr;
        int cs   = cc ^ ((n_r >> 1) & 7);
        wg_off[i] = (n0 + n_r) * 512 + cs * 8;
        wl_off[i] = (wv * 32 + i * 8) * 64;
    }

    // fragment offsets
    const int wave_n = (wv >> 1) * 64;
    const int wave_m = (wv & 1) * 64;
    int a_off[2][4], b_off[2][4];
#pragma unroll
    for (int ks = 0; ks < 2; ++ks) {
#pragma unroll
        for (int t2 = 0; t2 < 4; ++t2) {
            int n = wave_n + t2 * 16 + l15;
            a_off[ks][t2] = n * 64 + (((ks * 4 + quad) ^ ((n >> 1) & 7)) << 3);
            int m = wave_m + t2 * 16 + l15;
            b_off[ks][t2] = m * 64 + (((ks * 4 + quad) ^ ((m >> 1) & 7)) << 3);
        }
    }

    f32x4 acc[4][4];
#pragma unroll
    for (int a = 0; a < 4; ++a)
#pragma unroll
        for (int c = 0; c < 4; ++c) acc[a][c] = f32x4{0.f, 0.f, 0.f, 0.f};

    // ---- prologue: bias, gll W(0), X(0), X(1) — order pinned for vmcnt bookkeeping ----
    const int o_base = nblk * 32 + (wave_n >> 2) + quad;
    float bv[4];
#pragma unroll
    for (int tn = 0; tn < 4; ++tn) bv[tn] = bias[o_base + tn * 4];
    __builtin_amdgcn_sched_barrier(0);
#pragma unroll
    for (int i = 0; i < 4; ++i)
        __builtin_amdgcn_global_load_lds((AS1 void*)(wt + wg_off[i]),
                                         (AS3 void*)(&Ws[0][0] + wl_off[i]), 16, 0, 0);
    __builtin_amdgcn_sched_barrier(0);
    f32x4 v[2][8];
#pragma unroll
    for (int r = 0; r < 8; ++r) v[0][r] = *(const f32x4*)(xsrc + (size_t)r * 4096);
    __builtin_amdgcn_sched_barrier(0);
#pragma unroll
    for (int r = 0; r < 8; ++r) v[1][r] = *(const f32x4*)(xsrc + (size_t)(64 + r) * 4096);
    __builtin_amdgcn_sched_barrier(0);

#pragma unroll
    for (int kt = 0; kt < 8; ++kt) {
        // stage X(kt) from regs (compiler inserts precise vmcnt for v[kt&1]; leaves
        // gllW(kt) + X(kt+1) in flight)
#pragma unroll
        for (int mm = 0; mm < 4; ++mm) {
            u32x4 pk;
            pk.x = pack_rnd(v[kt & 1][0][mm], v[kt & 1][1][mm]);
            pk.y = pack_rnd(v[kt & 1][2][mm], v[kt & 1][3][mm]);
            pk.z = pack_rnd(v[kt & 1][4][mm], v[kt & 1][5][mm]);
            pk.w = pack_rnd(v[kt & 1][6][mm], v[kt & 1][7][mm]);
            *(u32x4*)(&Xs[0] + xw_off[mm]) = pk;
        }
        __builtin_amdgcn_sched_barrier(0);
        // Barrier A: lgkmcnt(0) [X writes visible] + vmcnt(8) [gllW(kt) done,
        // X(kt+1) stays in flight]. Tail kt=7: nothing to keep -> vmcnt(0).
        if (kt == 7) __builtin_amdgcn_s_waitcnt(0x0070);
        else         __builtin_amdgcn_s_waitcnt(0x0078);
        __builtin_amdgcn_s_barrier();
        __builtin_amdgcn_sched_barrier(0);

        if (kt < 7) { // gll W(kt+1) -> other buffer (issued first: oldest in queue)
            const uint16_t* wg = wt + (kt + 1) * 64;
            uint16_t* ldst = &Ws[(kt + 1) & 1][0];
#pragma unroll
            for (int i = 0; i < 4; ++i)
                __builtin_amdgcn_global_load_lds((AS1 void*)(wg + wg_off[i]),
                                                 (AS3 void*)(ldst + wl_off[i]), 16, 0, 0);
        }
        __builtin_amdgcn_sched_barrier(0);
        if (kt < 6) { // X(kt+2) -> regs, distance-2 prefetch (never force-drained)
            const float* xs = xsrc + (size_t)(kt + 2) * 64 * 4096;
#pragma unroll
            for (int r = 0; r < 8; ++r) v[kt & 1][r] = *(const f32x4*)(xs + (size_t)r * 4096);
        }
        __builtin_amdgcn_sched_barrier(0);

        const uint16_t* wb = &Ws[kt & 1][0];
#pragma unroll
        for (int ks = 0; ks < 2; ++ks) {
            bf16x8 af[4], bf[4];
#pragma unroll
            for (int t2 = 0; t2 < 4; ++t2) af[t2] = *(const bf16x8*)(wb + a_off[ks][t2]);
#pragma unroll
            for (int t2 = 0; t2 < 4; ++t2) bf[t2] = *(const bf16x8*)(&Xs[0] + b_off[ks][t2]);
#pragma unroll
            for (int tn = 0; tn < 4; ++tn)
#pragma unroll
                for (int tm = 0; tm < 4; ++tm)
                    acc[tn][tm] = __builtin_amdgcn_mfma_f32_16x16x32_bf16(
                        af[tn], bf[tm], acc[tn][tm], 0, 0, 0);
        }
        // Barrier B: bare. Frag reads already drained by MFMA deps; keeps
        // gllW(kt+1) + X(kt+2) in flight across the barrier.
        __builtin_amdgcn_s_barrier();
        __builtin_amdgcn_sched_barrier(0);
    }

    // ---- epilogue: 2x2 (i,j) per reg-quad; 16 lanes = consecutive w -> 128 B segments ----
    const int y_base = (mblk & 31) * 4;
    float* outb = out + (size_t)b * 256 * 16384;
#pragma unroll
    for (int tn = 0; tn < 4; ++tn) {
        int o = o_base + tn * 4;
#pragma unroll
        for (int tm = 0; tm < 4; ++tm) {
            int loc = wave_m + tm * 16 + l15;
            int hl  = loc >> 6;
            int ww  = loc & 63;
            float* p = outb + ((size_t)o * 128 + (y_base + 2 * hl)) * 128 + 2 * ww;
            f32x4 a = acc[tn][tm];
            float2 t0; t0.x = a.x + bv[tn]; t0.y = a.y + bv[tn];
            float2 t1; t1.x = a.z + bv[tn]; t1.y = a.w + bv[tn];
            *(float2*)(p)       = t0;
            *(float2*)(p + 128) = t1;
        }
    }
}

extern "C" void kernel_launch(void* const* d_in, const int* in_sizes, int n_in,
                              void* d_out, int out_size, void* d_ws, size_t ws_size,
                              hipStream_t stream) {
    const float* x    = (const float*)d_in[0];  // [8][512][64][64]
    const float* w    = (const float*)d_in[1];  // [512][256][2][2] = [512][1024]
    const float* bias = (const float*)d_in[2];  // [256]
    float* out        = (float*)d_out;          // [8][256][128][128]
    uint16_t* wt      = (uint16_t*)d_ws;        // [1024][512] bf16 (1 MiB)

    wt_prep<<<32, 256, 0, stream>>>(w, wt);
    tconv_gemm<<<2048, 256, 0, stream>>>(x, wt, bias, out);
}

// Round 3
// 250.792 us; speedup vs baseline: 1.0800x; 1.0800x over previous
//
#include <hip/hip_runtime.h>
#include <stdint.h>

#define AS1 __attribute__((address_space(1)))
#define AS3 __attribute__((address_space(3)))

typedef float   f32x4  __attribute__((ext_vector_type(4)));
typedef __bf16  bf16x8 __attribute__((ext_vector_type(8)));
typedef uint32_t u32x4 __attribute__((ext_vector_type(4)));

// Round-half-up fp32->bf16 pair pack: low16 = lo, high16 = hi.
__device__ __forceinline__ uint32_t pack_rnd(float lo, float hi) {
    uint32_t a = __float_as_uint(hi) + 0x8000u;
    uint32_t b = __float_as_uint(lo) + 0x8000u;
    return __builtin_amdgcn_perm(a, b, 0x07060302u); // bytes: a3 a2 b3 b2
}

// ---------------- wt_prep: w [512 c][1024 n] f32 -> wt [1024 n][512 c] bf16 ----------------
__global__ __launch_bounds__(256) void wt_prep(const float* __restrict__ w,
                                               uint16_t* __restrict__ wt) {
    __shared__ uint16_t tile[32][520];   // [n_local][c]; row = 1040 B (16 B multiple)
    const int tid = threadIdx.x;
    const int n0  = blockIdx.x * 32;
    const int nq  = tid & 7;
    const int cr  = tid >> 3;
#pragma unroll
    for (int p = 0; p < 16; ++p) {
        int c = p * 32 + cr;
        f32x4 q = *(const f32x4*)(w + (size_t)c * 1024 + n0 + nq * 4);
#pragma unroll
        for (int i = 0; i < 4; ++i)
            tile[nq * 4 + i][c] = (uint16_t)((__float_as_uint(q[i]) + 0x8000u) >> 16);
    }
    __syncthreads();
    const int l  = tid & 63;
    const int wv = tid >> 6;
#pragma unroll
    for (int rr = 0; rr < 8; ++rr) {
        int nl = wv * 8 + rr;
        u32x4 d = *(const u32x4*)&tile[nl][l * 8];
        *(u32x4*)(wt + (size_t)(n0 + nl) * 512 + l * 8) = d;   // wave = 1 KB contiguous
    }
}

// ---------------- Main kernel: D[n][m] = Wt · X, fused bias + pixel-shuffle ----------------
// BM=128, BN=128, BK=64, 256 threads (4 waves, each 64x64). Occupancy-first variant:
// 32 KB LDS (single-buffered W) + 128-reg budget -> 4 blocks/CU target.
__global__ __launch_bounds__(256, 4) void tconv_gemm(const float* __restrict__ x,
                                                     const uint16_t* __restrict__ wt,
                                                     const float* __restrict__ bias,
                                                     float* __restrict__ out) {
    __shared__ uint16_t Ws[8192];   // [128 n][64 k] bf16, 16 KB
    __shared__ uint16_t Xs[8192];   // [128 m][64 k] bf16, 16 KB

    const int tid  = threadIdx.x;
    const int l    = tid & 63;
    const int wv   = tid >> 6;
    const int l15  = l & 15;
    const int quad = l >> 4;

    // XCD-aware decode: 8 consecutive-jj blocks (same XCD) share one X m-tile.
    const int bid  = blockIdx.x;
    const int xcd  = bid & 7;
    const int jj   = bid >> 3;
    const int nblk = jj & 7;
    const int mblk = xcd * 32 + (jj >> 3);

    const int b  = mblk >> 5;
    const int p0 = (mblk & 31) * 128;
    const int n0 = nblk * 128;

    // X staging: thread covers 8 k-rows x 4 m (coalesced 512 B runs)
    const int mq4 = (tid & 31) * 4;
    const int ko  = tid >> 5;
    const float* xsrc = x + ((size_t)b * 512 + (size_t)ko * 8) * 4096 + p0 + mq4;
    int xw_off[4];
#pragma unroll
    for (int mm = 0; mm < 4; ++mm) {
        int m = mq4 + mm;
        xw_off[mm] = m * 64 + ((ko ^ ((m >> 1) & 7)) << 3);
    }

    // W gll: lane (rr,cc); XOR swizzle folded into the GLOBAL address; LDS dst wave-uniform.
    const int rr = l >> 3, cc = l & 7;
    int wg_off[4], wl_off[4];
#pragma unroll
    for (int i = 0; i < 4; ++i) {
        int n_r  = wv * 32 + i * 8 + rr;
        int cs   = cc ^ ((n_r >> 1) & 7);
        wg_off[i] = (n0 + n_r) * 512 + cs * 8;
        wl_off[i] = (wv * 32 + i * 8) * 64;
    }

    // fragment bases; t2 enters as +1024*t2 (folds into ds_read imm offset since
    // (n>>1)&7 is invariant under n += 16).
    const int wave_n = (wv >> 1) * 64;
    const int wave_m = (wv & 1) * 64;
    int a_base[2], b_base[2];
#pragma unroll
    for (int ks = 0; ks < 2; ++ks) {
        int n = wave_n + l15;
        a_base[ks] = n * 64 + (((ks * 4 + quad) ^ ((n >> 1) & 7)) << 3);
        int m = wave_m + l15;
        b_base[ks] = m * 64 + (((ks * 4 + quad) ^ ((m >> 1) & 7)) << 3);
    }

    f32x4 acc[4][4];
#pragma unroll
    for (int a = 0; a < 4; ++a)
#pragma unroll
        for (int c = 0; c < 4; ++c) acc[a][c] = f32x4{0.f, 0.f, 0.f, 0.f};

    // prologue: gll W(0); X(0) -> regs
#pragma unroll
    for (int i = 0; i < 4; ++i)
        __builtin_amdgcn_global_load_lds((AS1 void*)(wt + wg_off[i]),
                                         (AS3 void*)(Ws + wl_off[i]), 16, 0, 0);
    f32x4 v[8];
#pragma unroll
    for (int r = 0; r < 8; ++r) v[r] = *(const f32x4*)(xsrc + (size_t)r * 4096);

    for (int kt = 0; kt < 8; ++kt) {
        // stage X(kt) from regs (b128 writes; residual write conflicts = 3.6%, harmless)
#pragma unroll
        for (int mm = 0; mm < 4; ++mm) {
            u32x4 pk;
            pk.x = pack_rnd(v[0][mm], v[1][mm]);
            pk.y = pack_rnd(v[2][mm], v[3][mm]);
            pk.z = pack_rnd(v[4][mm], v[5][mm]);
            pk.w = pack_rnd(v[6][mm], v[7][mm]);
            *(u32x4*)(Xs + xw_off[mm]) = pk;
        }
        __syncthreads();   // A: staging visible + gll W(kt) done (issued ~150 cyc ago)

        if (kt < 7) {      // X(kt+1) -> regs; flies across the compute section
            const float* xs = xsrc + (size_t)(kt + 1) * 64 * 4096;
#pragma unroll
            for (int r = 0; r < 8; ++r) v[r] = *(const f32x4*)(xs + (size_t)r * 4096);
        }

#pragma unroll
        for (int ks = 0; ks < 2; ++ks) {
            bf16x8 af[4], bf[4];
#pragma unroll
            for (int t2 = 0; t2 < 4; ++t2) af[t2] = *(const bf16x8*)(Ws + a_base[ks] + t2 * 1024);
#pragma unroll
            for (int t2 = 0; t2 < 4; ++t2) bf[t2] = *(const bf16x8*)(Xs + b_base[ks] + t2 * 1024);
#pragma unroll
            for (int tn = 0; tn < 4; ++tn)
#pragma unroll
                for (int tm = 0; tm < 4; ++tm)
                    acc[tn][tm] = __builtin_amdgcn_mfma_f32_16x16x32_bf16(
                        af[tn], bf[tm], acc[tn][tm], 0, 0, 0);
        }
        __syncthreads();   // B: compute done -> Ws free for overwrite; drains X(kt+1) (covered)

        if (kt < 7) {      // gll W(kt+1) into the single W buffer; completes by next A
            const uint16_t* wg = wt + (kt + 1) * 64;
#pragma unroll
            for (int i = 0; i < 4; ++i)
                __builtin_amdgcn_global_load_lds((AS1 void*)(wg + wg_off[i]),
                                                 (AS3 void*)(Ws + wl_off[i]), 16, 0, 0);
        }
    }

    // epilogue: bias loaded here (keeps loop VGPRs down); 2x2 (i,j) per reg-quad;
    // 16 lanes = consecutive w -> contiguous 128 B segments, zero write amplification.
    const int o_base = nblk * 32 + (wave_n >> 2) + quad;
    const int y_base = (mblk & 31) * 4;
    float bv[4];
#pragma unroll
    for (int tn = 0; tn < 4; ++tn) bv[tn] = bias[o_base + tn * 4];
    float* outb = out + (size_t)b * 256 * 16384;
#pragma unroll
    for (int tn = 0; tn < 4; ++tn) {
        int o = o_base + tn * 4;
#pragma unroll
        for (int tm = 0; tm < 4; ++tm) {
            int loc = wave_m + tm * 16 + l15;
            int hl  = loc >> 6;
            int ww  = loc & 63;
            float* p = outb + ((size_t)o * 128 + (y_base + 2 * hl)) * 128 + 2 * ww;
            f32x4 a = acc[tn][tm];
            float2 t0; t0.x = a.x + bv[tn]; t0.y = a.y + bv[tn];
            float2 t1; t1.x = a.z + bv[tn]; t1.y = a.w + bv[tn];
            *(float2*)(p)       = t0;
            *(float2*)(p + 128) = t1;
        }
    }
}

extern "C" void kernel_launch(void* const* d_in, const int* in_sizes, int n_in,
                              void* d_out, int out_size, void* d_ws, size_t ws_size,
                              hipStream_t stream) {
    const float* x    = (const float*)d_in[0];  // [8][512][64][64]
    const float* w    = (const float*)d_in[1];  // [512][256][2][2] = [512][1024]
    const float* bias = (const float*)d_in[2];  // [256]
    float* out        = (float*)d_out;          // [8][256][128][128]
    uint16_t* wt      = (uint16_t*)d_ws;        // [1024][512] bf16 (1 MiB)

    wt_prep<<<32, 256, 0, stream>>>(w, wt);
    tconv_gemm<<<2048, 256, 0, stream>>>(x, wt, bias, out);
}